// Round 8
// baseline (2424.630 us; speedup 1.0000x reference)
//
#include <hip/hip_runtime.h>
#include <math.h>

#define NODES 50000
#define NEDGE 800000
#define ETOT  (NEDGE + NODES)
#define NEGF  -1e30f   // finite -inf sentinel
#define CAP   96       // per-wave LDS edge cache (max degree ~45 for this graph)
#define FB    ((ETOT + 255) / 256)    // fill-role blocks
#define GBLK  ((NODES + 31) / 32)     // gemm-role blocks

typedef unsigned short ushort_t;
typedef unsigned int uint_t;

__device__ __forceinline__ ushort_t f2bf(float f) {   // fp32 -> bf16 RNE
    uint_t u = __float_as_uint(f);
    return (ushort_t)((u + 0x7fffu + ((u >> 16) & 1u)) >> 16);
}

// ---- fused: csr_fill (blocks [0,FB)) + GEMM1+alpha (blocks [FB,FB+GBLK)) ----
// gemm: 32 rows/block, 256 thr, acc[4][4], W software-pipelined in registers
__global__ void gemm1_fill(const float* __restrict__ X, const float* __restrict__ W,
                           const float* __restrict__ a_src, const float* __restrict__ a_dst,
                           ushort_t* __restrict__ Hb, float* __restrict__ as_,
                           float* __restrict__ ad_,
                           const int* __restrict__ ei, int* __restrict__ cursor,
                           ushort_t* __restrict__ srcs, int n) {
    __shared__ float xs[32][132];      // stride 132: 16B-aligned rows for b128 reads
    if (blockIdx.x < FB) {
        // ---- csr_fill role ----
        int e = blockIdx.x * 256 + threadIdx.x;
        if (e < ETOT) {
            int s, d;
            if (e < NEDGE) { s = ei[e]; d = ei[NEDGE + e]; }
            else           { s = d = e - NEDGE; }
            int pos = atomicAdd(&cursor[d], 1);
            srcs[pos] = (ushort_t)s;
        }
        return;
    }
    // ---- gemm role ----
    const int t = threadIdx.x;         // 0..255
    const int ct = t & 31;             // col group: cols ct, ct+32, ct+64, ct+96
    const int rg = t >> 5;             // row group 0..7 -> rows rg*4..rg*4+3
    const int row0 = (blockIdx.x - FB) * 32;
    #pragma unroll
    for (int i = 0; i < 16; ++i) {
        int idx = i * 256 + t;
        int r = idx >> 7, c = idx & 127;
        int row = row0 + r;
        xs[r][c] = (row < n) ? X[(size_t)row * 128 + c] : 0.f;
    }
    __syncthreads();
    float acc[4][4];
    #pragma unroll
    for (int r = 0; r < 4; ++r)
        #pragma unroll
        for (int c = 0; c < 4; ++c) acc[r][c] = 0.f;

    float wA[8][4], wB[8][4];
    const float* Wc = W + ct;
    auto loadw = [&](float (&buf)[8][4], int kb) {
        #pragma unroll
        for (int kk = 0; kk < 8; ++kk) {
            const float* wp = Wc + (size_t)(kb + kk) * 128;
            buf[kk][0] = wp[0];  buf[kk][1] = wp[32];
            buf[kk][2] = wp[64]; buf[kk][3] = wp[96];
        }
    };
    auto comp = [&](float (&buf)[8][4], int kb) {
        #pragma unroll
        for (int q = 0; q < 2; ++q) {
            float4 xv[4];
            #pragma unroll
            for (int r = 0; r < 4; ++r)
                xv[r] = *(const float4*)(&xs[rg * 4 + r][kb + q * 4]);
            #pragma unroll
            for (int k2 = 0; k2 < 4; ++k2) {
                #pragma unroll
                for (int r = 0; r < 4; ++r) {
                    float xvk = (k2 == 0) ? xv[r].x : (k2 == 1) ? xv[r].y
                              : (k2 == 2) ? xv[r].z : xv[r].w;
                    acc[r][0] += xvk * buf[q * 4 + k2][0];
                    acc[r][1] += xvk * buf[q * 4 + k2][1];
                    acc[r][2] += xvk * buf[q * 4 + k2][2];
                    acc[r][3] += xvk * buf[q * 4 + k2][3];
                }
            }
        }
    };
    loadw(wA, 0);
    #pragma unroll
    for (int g = 0; g < 16; g += 2) {     // software pipeline: load next, compute cur
        loadw(wB, (g + 1) * 8);
        comp(wA, g * 8);
        if (g + 2 < 16) loadw(wA, (g + 2) * 8);
        comp(wB, (g + 1) * 8);
    }
    #pragma unroll
    for (int r = 0; r < 4; ++r) {
        int row = row0 + rg * 4 + r;
        bool ok = row < n;
        float s = 0.f, d = 0.f;
        #pragma unroll
        for (int c = 0; c < 4; ++c) {
            float v = acc[r][c];
            int col = ct + 32 * c;
            if (ok) Hb[(size_t)row * 128 + col] = f2bf(v);
            s += v * a_src[col];
            d += v * a_dst[col];
        }
        #pragma unroll
        for (int off = 16; off; off >>= 1) {            // reduce across the 32-lane col group
            s += __shfl_down(s, off, 32);
            d += __shfl_down(d, off, 32);
        }
        if (ct == 0 && ok) { as_[row] = s; ad_[row] = d; }
    }
}

// ---- GEMM2 + fused alpha: H2[n,16] = Hin @ W2 (W2 staged in LDS) ----
__global__ void gemm_hw2_alpha(const float* __restrict__ Hin, const float* __restrict__ W,
                               const float* __restrict__ a_src, const float* __restrict__ a_dst,
                               float* __restrict__ Hout, float* __restrict__ as_,
                               float* __restrict__ ad_, int n) {
    __shared__ float wl[128 * 16];
    for (int i = threadIdx.x; i < 128 * 16; i += 256) wl[i] = W[i];
    __syncthreads();
    int tid = blockIdx.x * blockDim.x + threadIdx.x;
    int node = tid >> 4, col = tid & 15;
    if (node >= n) return;
    const float* hr = Hin + (size_t)node * 128;
    float acc = 0.f;
    #pragma unroll
    for (int k = 0; k < 128; ++k) acc += hr[k] * wl[k * 16 + col];
    Hout[(size_t)node * 16 + col] = acc;
    float ps = acc * a_src[col], pd = acc * a_dst[col];
    #pragma unroll
    for (int off = 1; off < 16; off <<= 1) {
        ps += __shfl_xor(ps, off);
        pd += __shfl_xor(pd, off);
    }
    if (col == 0) { as_[node] = ps; ad_[node] = pd; }
}

// =================== CSR build ====================
__global__ void csr_hist(const int* __restrict__ ei, int* __restrict__ deg) {
    int e = blockIdx.x * blockDim.x + threadIdx.x;
    if (e >= ETOT) return;
    int d = (e < NEDGE) ? ei[NEDGE + e] : e - NEDGE;
    atomicAdd(&deg[d], 1);
}

__global__ void scan1(const int* __restrict__ deg, int* __restrict__ bsum) {
    int i = blockIdx.x * 256 + threadIdx.x;
    int v = (i < NODES) ? deg[i] : 0;
    #pragma unroll
    for (int off = 32; off; off >>= 1) v += __shfl_down(v, off);
    __shared__ int ws[4];
    if ((threadIdx.x & 63) == 0) ws[threadIdx.x >> 6] = v;
    __syncthreads();
    if (threadIdx.x == 0) bsum[blockIdx.x] = ws[0] + ws[1] + ws[2] + ws[3];
}

__global__ void scan2(int* __restrict__ bsum, int nb) {
    int t = threadIdx.x;
    int lane = t & 63, w = t >> 6;
    int v = (t < nb) ? bsum[t] : 0;
    int sv = v;
    #pragma unroll
    for (int off = 1; off < 64; off <<= 1) {
        int o = __shfl_up(sv, off);
        if (lane >= off) sv += o;
    }
    __shared__ int wsum[4];
    if (lane == 63) wsum[w] = sv;
    __syncthreads();
    int add = 0;
    for (int j = 0; j < w; ++j) add += wsum[j];
    sv += add;
    if (t < nb) bsum[t] = sv - v;   // exclusive
}

__global__ void scan3(const int* __restrict__ deg, const int* __restrict__ bsum,
                      int* __restrict__ rowptr, int* __restrict__ cursor) {
    int i = blockIdx.x * 256 + threadIdx.x;
    int v = (i < NODES) ? deg[i] : 0;
    int lane = threadIdx.x & 63, w = threadIdx.x >> 6;
    int sv = v;
    #pragma unroll
    for (int off = 1; off < 64; off <<= 1) {
        int o = __shfl_up(sv, off);
        if (lane >= off) sv += o;
    }
    __shared__ int wsum[4];
    if (lane == 63) wsum[w] = sv;
    __syncthreads();
    int add = bsum[blockIdx.x];
    for (int j = 0; j < w; ++j) add += wsum[j];
    int excl = add + sv - v;
    if (i < NODES) { rowptr[i] = excl; cursor[i] = excl; }
    if (i == NODES - 1) rowptr[NODES] = excl + v;
}

// ---- layer 1: fused softmax + weighted bf16 gather + bias + ReLU (F=128) ----
__global__ void gat_fused128(const int* __restrict__ rowptr, const ushort_t* __restrict__ srcs,
                             const float* __restrict__ as_, const float* __restrict__ ad_,
                             const ushort_t* __restrict__ Hb, const float* __restrict__ b,
                             float* __restrict__ out) {
    __shared__ float sw[4][CAP];
    __shared__ int   ss[4][CAP];
    int wid = (blockIdx.x * blockDim.x + threadIdx.x) >> 6;
    int lane = threadIdx.x & 63;
    int wv = (threadIdx.x >> 6) & 3;
    if (wid >= NODES) return;
    const int beg = rowptr[wid], deg = rowptr[wid + 1] - beg;
    const float adv = ad_[wid];
    float m = NEGF;
    for (int i = lane; i < deg; i += 64) {
        int s = srcs[beg + i];
        float v = as_[s] + adv;
        v = (v >= 0.f) ? v : 0.2f * v;
        if (i < CAP) { sw[wv][i] = v; ss[wv][i] = s; }
        m = fmaxf(m, v);
    }
    #pragma unroll
    for (int off = 32; off; off >>= 1) m = fmaxf(m, __shfl_xor(m, off));
    float den = 0.f;
    for (int i = lane; i < deg; i += 64) {
        float v;
        if (i < CAP) v = sw[wv][i];
        else { int s = srcs[beg + i]; v = as_[s] + adv; v = (v >= 0.f) ? v : 0.2f * v; }
        float w = __expf(v - m);
        if (i < CAP) sw[wv][i] = w;
        den += w;
    }
    #pragma unroll
    for (int off = 32; off; off >>= 1) den += __shfl_xor(den, off);
    const float invd = 1.f / (den + 1e-16f);
    // phase 2: weighted gather of bf16 rows; lane covers features {2l, 2l+1}
    float ax = 0.f, ay = 0.f;
    const int nl = deg < CAP ? deg : CAP;
    int i = 0;
    for (; i + 4 <= nl; i += 4) {
        float w0 = sw[wv][i], w1 = sw[wv][i + 1], w2 = sw[wv][i + 2], w3 = sw[wv][i + 3];
        int s0 = ss[wv][i], s1 = ss[wv][i + 1], s2 = ss[wv][i + 2], s3 = ss[wv][i + 3];
        uint_t u0 = *(const uint_t*)(Hb + (size_t)s0 * 128 + lane * 2);
        uint_t u1 = *(const uint_t*)(Hb + (size_t)s1 * 128 + lane * 2);
        uint_t u2 = *(const uint_t*)(Hb + (size_t)s2 * 128 + lane * 2);
        uint_t u3 = *(const uint_t*)(Hb + (size_t)s3 * 128 + lane * 2);
        ax += w0 * __uint_as_float(u0 << 16) + w1 * __uint_as_float(u1 << 16)
            + w2 * __uint_as_float(u2 << 16) + w3 * __uint_as_float(u3 << 16);
        ay += w0 * __uint_as_float(u0 & 0xffff0000u) + w1 * __uint_as_float(u1 & 0xffff0000u)
            + w2 * __uint_as_float(u2 & 0xffff0000u) + w3 * __uint_as_float(u3 & 0xffff0000u);
    }
    for (; i < nl; ++i) {
        float w0 = sw[wv][i];
        int s0 = ss[wv][i];
        uint_t u0 = *(const uint_t*)(Hb + (size_t)s0 * 128 + lane * 2);
        ax += w0 * __uint_as_float(u0 << 16);
        ay += w0 * __uint_as_float(u0 & 0xffff0000u);
    }
    for (int j = CAP; j < deg; ++j) {   // correctness fallback, ~never taken
        int s0 = srcs[beg + j];
        float v = as_[s0] + adv; v = (v >= 0.f) ? v : 0.2f * v;
        float w0 = __expf(v - m);
        uint_t u0 = *(const uint_t*)(Hb + (size_t)s0 * 128 + lane * 2);
        ax += w0 * __uint_as_float(u0 << 16);
        ay += w0 * __uint_as_float(u0 & 0xffff0000u);
    }
    float2 o;
    o.x = fmaxf(ax * invd + b[lane * 2], 0.f);
    o.y = fmaxf(ay * invd + b[lane * 2 + 1], 0.f);
    *(float2*)(out + (size_t)wid * 128 + lane * 2) = o;
}

// ---- layer 2: fused softmax + aggregate (F=16, 4 slots/wave) + bias + lsm ----
__global__ void gat_fused16_lsm(const int* __restrict__ rowptr, const ushort_t* __restrict__ srcs,
                                const float* __restrict__ as_, const float* __restrict__ ad_,
                                const float* __restrict__ H, const float* __restrict__ b,
                                float* __restrict__ out) {
    __shared__ float sw[4][CAP];
    __shared__ int   ss[4][CAP];
    int wid = (blockIdx.x * blockDim.x + threadIdx.x) >> 6;
    int lane = threadIdx.x & 63;
    int wv = (threadIdx.x >> 6) & 3;
    int slot = lane >> 4, k = lane & 15;
    if (wid >= NODES) return;
    const int beg = rowptr[wid], deg = rowptr[wid + 1] - beg;
    const float adv = ad_[wid];
    float m = NEGF;
    for (int i = lane; i < deg; i += 64) {
        int s = srcs[beg + i];
        float v = as_[s] + adv;
        v = (v >= 0.f) ? v : 0.2f * v;
        if (i < CAP) { sw[wv][i] = v; ss[wv][i] = s; }
        m = fmaxf(m, v);
    }
    #pragma unroll
    for (int off = 32; off; off >>= 1) m = fmaxf(m, __shfl_xor(m, off));
    float den = 0.f;
    for (int i = lane; i < deg; i += 64) {
        float v;
        if (i < CAP) v = sw[wv][i];
        else { int s = srcs[beg + i]; v = as_[s] + adv; v = (v >= 0.f) ? v : 0.2f * v; }
        float w = __expf(v - m);
        if (i < CAP) sw[wv][i] = w;
        den += w;
    }
    #pragma unroll
    for (int off = 32; off; off >>= 1) den += __shfl_xor(den, off);
    const float invd = 1.f / (den + 1e-16f);
    float acc = 0.f;
    const int nl = deg < CAP ? deg : CAP;
    for (int i = slot; i < nl; i += 4) {
        acc += sw[wv][i] * H[(size_t)ss[wv][i] * 16 + k];
    }
    for (int j = CAP + slot; j < deg; j += 4) {   // fallback, ~never taken
        int s = srcs[beg + j];
        float v = as_[s] + adv; v = (v >= 0.f) ? v : 0.2f * v;
        acc += __expf(v - m) * H[(size_t)s * 16 + k];
    }
    acc += __shfl_xor(acc, 16);
    acc += __shfl_xor(acc, 32);
    float v = acc * invd + b[k];
    float mx = v;
    #pragma unroll
    for (int off = 1; off < 16; off <<= 1) mx = fmaxf(mx, __shfl_xor(mx, off));
    float ex = __expf(v - mx), ssum = ex;
    #pragma unroll
    for (int off = 1; off < 16; off <<= 1) ssum += __shfl_xor(ssum, off);
    float r = v - mx - __logf(ssum);
    if (lane < 16) out[(size_t)wid * 16 + k] = r;
}

extern "C" void kernel_launch(void* const* d_in, const int* in_sizes, int n_in,
                              void* d_out, int out_size, void* d_ws, size_t ws_size,
                              hipStream_t stream) {
    const float* x      = (const float*)d_in[0];
    const int*   ei     = (const int*)d_in[1];   // [2, E] int32 on device
    const float* W1     = (const float*)d_in[2];
    const float* a_src1 = (const float*)d_in[3];
    const float* a_dst1 = (const float*)d_in[4];
    const float* b1     = (const float*)d_in[5];
    const float* W2     = (const float*)d_in[6];
    const float* a_src2 = (const float*)d_in[7];
    const float* a_dst2 = (const float*)d_in[8];
    const float* b2     = (const float*)d_in[9];
    float* out = (float*)d_out;

    // ---- workspace layout ----
    float* p = (float*)d_ws;
    ushort_t* h1b = (ushort_t*)p; p += (size_t)NODES * 64;   // 12.8 MB as bf16
    float* agg1   = p; p += (size_t)NODES * 128;             // 25.6 MB
    float* h2     = p; p += (size_t)NODES * 16;              //  3.2 MB
    float* as_    = p; p += NODES;
    float* ad_    = p; p += NODES;
    int* ip = (int*)p;
    int* deg    = ip; ip += NODES;
    int* cursor = ip; ip += NODES;
    int* rowptr = ip; ip += NODES + 1;
    ushort_t* srcs = (ushort_t*)ip; ip += (ETOT + 1) / 2;
    int* bsum   = ip; ip += 256;

    const int EB = (ETOT + 255) / 256;
    const int NB = (NODES + 255) / 256;   // 196 chunks
    const int WAVEGRID = (NODES * 64 + 255) / 256;

    // ---- CSR build prefix (hist + scan) ----
    hipMemsetAsync(deg, 0, NODES * sizeof(int), stream);
    csr_hist<<<EB, 256, 0, stream>>>(ei, deg);
    scan1<<<NB, 256, 0, stream>>>(deg, bsum);
    scan2<<<1, 256, 0, stream>>>(bsum, NB);
    scan3<<<NB, 256, 0, stream>>>(deg, bsum, rowptr, cursor);

    // ---- fused: csr_fill + GEMM1+alpha (independent work, one dispatch) ----
    gemm1_fill<<<FB + GBLK, 256, 0, stream>>>(x, W1, a_src1, a_dst1, h1b, as_, ad_,
                                              ei, cursor, srcs, NODES);

    // ---- layer 1 aggregate ----
    gat_fused128<<<WAVEGRID, 256, 0, stream>>>(rowptr, srcs, as_, ad_, h1b, b1, agg1);

    // ---- layer 2 ----
    gemm_hw2_alpha<<<(NODES * 16 + 255) / 256, 256, 0, stream>>>(agg1, W2, a_src2, a_dst2, h2, as_, ad_, NODES);
    gat_fused16_lsm<<<WAVEGRID, 256, 0, stream>>>(rowptr, srcs, as_, ad_, h2, b2, out);
}

// Round 9
// 230.781 us; speedup vs baseline: 10.5062x; 10.5062x over previous
//
#include <hip/hip_runtime.h>
#include <math.h>

#define NODES 50000
#define NEDGE 800000
#define ETOT  (NEDGE + NODES)
#define NEGF  -1e30f   // finite -inf sentinel
#define CAP   96       // per-wave LDS edge cache (max degree ~45 for this graph)
#define FB    ((ETOT + 255) / 256)    // fill-role blocks
#define GBLK  ((NODES + 31) / 32)     // gemm-role blocks

typedef unsigned short ushort_t;
typedef unsigned int uint_t;

__device__ __forceinline__ ushort_t f2bf(float f) {   // fp32 -> bf16 RNE
    uint_t u = __float_as_uint(f);
    return (ushort_t)((u + 0x7fffu + ((u >> 16) & 1u)) >> 16);
}

// ---- fused: csr_fill (blocks [0,FB)) + GEMM1+alpha (blocks [FB,FB+GBLK)) ----
// gemm role: 32 rows/block, 256 thr, acc[4][4] over 4 CONTIGUOUS cols (float4 W)
__global__ void gemm1_fill(const float* __restrict__ X, const float* __restrict__ W,
                           const float* __restrict__ a_src, const float* __restrict__ a_dst,
                           ushort_t* __restrict__ Hb, float* __restrict__ as_,
                           float* __restrict__ ad_,
                           const int* __restrict__ ei, int* __restrict__ cursor,
                           ushort_t* __restrict__ srcs, int n) {
    __shared__ float xs[32][132];      // stride 132: 16B-aligned rows for b128 reads
    if (blockIdx.x < FB) {
        // ---- csr_fill role ----
        int e = blockIdx.x * 256 + threadIdx.x;
        if (e < ETOT) {
            int s, d;
            if (e < NEDGE) { s = ei[e]; d = ei[NEDGE + e]; }
            else           { s = d = e - NEDGE; }
            int pos = atomicAdd(&cursor[d], 1);
            srcs[pos] = (ushort_t)s;
        }
        return;
    }
    // ---- gemm role ----
    const int t = threadIdx.x;         // 0..255
    const int ct = t & 31;             // cols 4*ct .. 4*ct+3 (contiguous)
    const int rg = t >> 5;             // row group 0..7 -> rows rg*4..rg*4+3
    const int row0 = (blockIdx.x - FB) * 32;
    #pragma unroll
    for (int i = 0; i < 16; ++i) {
        int idx = i * 256 + t;
        int r = idx >> 7, c = idx & 127;
        int row = row0 + r;
        xs[r][c] = (row < n) ? X[(size_t)row * 128 + c] : 0.f;
    }
    __syncthreads();
    float acc[4][4];
    #pragma unroll
    for (int r = 0; r < 4; ++r)
        #pragma unroll
        for (int c = 0; c < 4; ++c) acc[r][c] = 0.f;

    const float* Wp = W + 4 * ct;
    for (int k4 = 0; k4 < 32; ++k4) {
        float4 w0 = *(const float4*)(Wp + (size_t)(k4 * 4 + 0) * 128);
        float4 w1 = *(const float4*)(Wp + (size_t)(k4 * 4 + 1) * 128);
        float4 w2 = *(const float4*)(Wp + (size_t)(k4 * 4 + 2) * 128);
        float4 w3 = *(const float4*)(Wp + (size_t)(k4 * 4 + 3) * 128);
        float4 xv[4];
        #pragma unroll
        for (int r = 0; r < 4; ++r)
            xv[r] = *(const float4*)(&xs[rg * 4 + r][k4 * 4]);
        #pragma unroll
        for (int r = 0; r < 4; ++r) {
            acc[r][0] += xv[r].x * w0.x + xv[r].y * w1.x + xv[r].z * w2.x + xv[r].w * w3.x;
            acc[r][1] += xv[r].x * w0.y + xv[r].y * w1.y + xv[r].z * w2.y + xv[r].w * w3.y;
            acc[r][2] += xv[r].x * w0.z + xv[r].y * w1.z + xv[r].z * w2.z + xv[r].w * w3.z;
            acc[r][3] += xv[r].x * w0.w + xv[r].y * w1.w + xv[r].z * w2.w + xv[r].w * w3.w;
        }
    }
    const float4 asv = *(const float4*)(a_src + 4 * ct);
    const float4 adv = *(const float4*)(a_dst + 4 * ct);
    #pragma unroll
    for (int r = 0; r < 4; ++r) {
        int row = row0 + rg * 4 + r;
        bool ok = row < n;
        if (ok) {
            uint_t lo = (uint_t)f2bf(acc[r][0]) | ((uint_t)f2bf(acc[r][1]) << 16);
            uint_t hi = (uint_t)f2bf(acc[r][2]) | ((uint_t)f2bf(acc[r][3]) << 16);
            uint2 pk; pk.x = lo; pk.y = hi;
            *(uint2*)(Hb + (size_t)row * 128 + 4 * ct) = pk;
        }
        float s = acc[r][0] * asv.x + acc[r][1] * asv.y + acc[r][2] * asv.z + acc[r][3] * asv.w;
        float d = acc[r][0] * adv.x + acc[r][1] * adv.y + acc[r][2] * adv.z + acc[r][3] * adv.w;
        #pragma unroll
        for (int off = 16; off; off >>= 1) {            // reduce across the 32-lane col group
            s += __shfl_down(s, off, 32);
            d += __shfl_down(d, off, 32);
        }
        if (ct == 0 && ok) { as_[row] = s; ad_[row] = d; }
    }
}

// ---- GEMM2 + fused alpha: H2[n,16] = Hin @ W2 (W2 staged in LDS) ----
__global__ void gemm_hw2_alpha(const float* __restrict__ Hin, const float* __restrict__ W,
                               const float* __restrict__ a_src, const float* __restrict__ a_dst,
                               float* __restrict__ Hout, float* __restrict__ as_,
                               float* __restrict__ ad_, int n) {
    __shared__ float wl[128 * 16];
    for (int i = threadIdx.x; i < 128 * 16; i += 256) wl[i] = W[i];
    __syncthreads();
    int tid = blockIdx.x * blockDim.x + threadIdx.x;
    int node = tid >> 4, col = tid & 15;
    if (node >= n) return;
    const float* hr = Hin + (size_t)node * 128;
    float acc = 0.f;
    #pragma unroll
    for (int k = 0; k < 128; ++k) acc += hr[k] * wl[k * 16 + col];
    Hout[(size_t)node * 16 + col] = acc;
    float ps = acc * a_src[col], pd = acc * a_dst[col];
    #pragma unroll
    for (int off = 1; off < 16; off <<= 1) {
        ps += __shfl_xor(ps, off);
        pd += __shfl_xor(pd, off);
    }
    if (col == 0) { as_[node] = ps; ad_[node] = pd; }
}

// =================== CSR build ====================
__global__ void csr_hist(const int* __restrict__ ei, int* __restrict__ deg) {
    int e = blockIdx.x * blockDim.x + threadIdx.x;
    if (e >= ETOT) return;
    int d = (e < NEDGE) ? ei[NEDGE + e] : e - NEDGE;
    atomicAdd(&deg[d], 1);
}

__global__ void scan1(const int* __restrict__ deg, int* __restrict__ bsum) {
    int i = blockIdx.x * 256 + threadIdx.x;
    int v = (i < NODES) ? deg[i] : 0;
    #pragma unroll
    for (int off = 32; off; off >>= 1) v += __shfl_down(v, off);
    __shared__ int ws[4];
    if ((threadIdx.x & 63) == 0) ws[threadIdx.x >> 6] = v;
    __syncthreads();
    if (threadIdx.x == 0) bsum[blockIdx.x] = ws[0] + ws[1] + ws[2] + ws[3];
}

__global__ void scan2(int* __restrict__ bsum, int nb) {
    int t = threadIdx.x;
    int lane = t & 63, w = t >> 6;
    int v = (t < nb) ? bsum[t] : 0;
    int sv = v;
    #pragma unroll
    for (int off = 1; off < 64; off <<= 1) {
        int o = __shfl_up(sv, off);
        if (lane >= off) sv += o;
    }
    __shared__ int wsum[4];
    if (lane == 63) wsum[w] = sv;
    __syncthreads();
    int add = 0;
    for (int j = 0; j < w; ++j) add += wsum[j];
    sv += add;
    if (t < nb) bsum[t] = sv - v;   // exclusive
}

__global__ void scan3(const int* __restrict__ deg, const int* __restrict__ bsum,
                      int* __restrict__ rowptr, int* __restrict__ cursor) {
    int i = blockIdx.x * 256 + threadIdx.x;
    int v = (i < NODES) ? deg[i] : 0;
    int lane = threadIdx.x & 63, w = threadIdx.x >> 6;
    int sv = v;
    #pragma unroll
    for (int off = 1; off < 64; off <<= 1) {
        int o = __shfl_up(sv, off);
        if (lane >= off) sv += o;
    }
    __shared__ int wsum[4];
    if (lane == 63) wsum[w] = sv;
    __syncthreads();
    int add = bsum[blockIdx.x];
    for (int j = 0; j < w; ++j) add += wsum[j];
    int excl = add + sv - v;
    if (i < NODES) { rowptr[i] = excl; cursor[i] = excl; }
    if (i == NODES - 1) rowptr[NODES] = excl + v;
}

// ---- layer 1: fused softmax + weighted bf16 gather + bias + ReLU (F=128) ----
__global__ void gat_fused128(const int* __restrict__ rowptr, const ushort_t* __restrict__ srcs,
                             const float* __restrict__ as_, const float* __restrict__ ad_,
                             const ushort_t* __restrict__ Hb, const float* __restrict__ b,
                             float* __restrict__ out) {
    __shared__ float sw[4][CAP];
    __shared__ int   ss[4][CAP];
    int wid = (blockIdx.x * blockDim.x + threadIdx.x) >> 6;
    int lane = threadIdx.x & 63;
    int wv = (threadIdx.x >> 6) & 3;
    if (wid >= NODES) return;
    const int beg = rowptr[wid], deg = rowptr[wid + 1] - beg;
    const float adv = ad_[wid];
    float m = NEGF;
    for (int i = lane; i < deg; i += 64) {
        int s = srcs[beg + i];
        float v = as_[s] + adv;
        v = (v >= 0.f) ? v : 0.2f * v;
        if (i < CAP) { sw[wv][i] = v; ss[wv][i] = s; }
        m = fmaxf(m, v);
    }
    #pragma unroll
    for (int off = 32; off; off >>= 1) m = fmaxf(m, __shfl_xor(m, off));
    float den = 0.f;
    for (int i = lane; i < deg; i += 64) {
        float v;
        if (i < CAP) v = sw[wv][i];
        else { int s = srcs[beg + i]; v = as_[s] + adv; v = (v >= 0.f) ? v : 0.2f * v; }
        float w = __expf(v - m);
        if (i < CAP) sw[wv][i] = w;
        den += w;
    }
    #pragma unroll
    for (int off = 32; off; off >>= 1) den += __shfl_xor(den, off);
    const float invd = 1.f / (den + 1e-16f);
    // phase 2: weighted gather of bf16 rows; lane covers features {2l, 2l+1}
    float ax = 0.f, ay = 0.f;
    const int nl = deg < CAP ? deg : CAP;
    int i = 0;
    for (; i + 4 <= nl; i += 4) {
        float w0 = sw[wv][i], w1 = sw[wv][i + 1], w2 = sw[wv][i + 2], w3 = sw[wv][i + 3];
        int s0 = ss[wv][i], s1 = ss[wv][i + 1], s2 = ss[wv][i + 2], s3 = ss[wv][i + 3];
        uint_t u0 = *(const uint_t*)(Hb + (size_t)s0 * 128 + lane * 2);
        uint_t u1 = *(const uint_t*)(Hb + (size_t)s1 * 128 + lane * 2);
        uint_t u2 = *(const uint_t*)(Hb + (size_t)s2 * 128 + lane * 2);
        uint_t u3 = *(const uint_t*)(Hb + (size_t)s3 * 128 + lane * 2);
        ax += w0 * __uint_as_float(u0 << 16) + w1 * __uint_as_float(u1 << 16)
            + w2 * __uint_as_float(u2 << 16) + w3 * __uint_as_float(u3 << 16);
        ay += w0 * __uint_as_float(u0 & 0xffff0000u) + w1 * __uint_as_float(u1 & 0xffff0000u)
            + w2 * __uint_as_float(u2 & 0xffff0000u) + w3 * __uint_as_float(u3 & 0xffff0000u);
    }
    for (; i < nl; ++i) {
        float w0 = sw[wv][i];
        int s0 = ss[wv][i];
        uint_t u0 = *(const uint_t*)(Hb + (size_t)s0 * 128 + lane * 2);
        ax += w0 * __uint_as_float(u0 << 16);
        ay += w0 * __uint_as_float(u0 & 0xffff0000u);
    }
    for (int j = CAP; j < deg; ++j) {   // correctness fallback, ~never taken
        int s0 = srcs[beg + j];
        float v = as_[s0] + adv; v = (v >= 0.f) ? v : 0.2f * v;
        float w0 = __expf(v - m);
        uint_t u0 = *(const uint_t*)(Hb + (size_t)s0 * 128 + lane * 2);
        ax += w0 * __uint_as_float(u0 << 16);
        ay += w0 * __uint_as_float(u0 & 0xffff0000u);
    }
    float2 o;
    o.x = fmaxf(ax * invd + b[lane * 2], 0.f);
    o.y = fmaxf(ay * invd + b[lane * 2 + 1], 0.f);
    *(float2*)(out + (size_t)wid * 128 + lane * 2) = o;
}

// ---- layer 2: fused softmax + aggregate (F=16, 4 slots/wave) + bias + lsm ----
__global__ void gat_fused16_lsm(const int* __restrict__ rowptr, const ushort_t* __restrict__ srcs,
                                const float* __restrict__ as_, const float* __restrict__ ad_,
                                const float* __restrict__ H, const float* __restrict__ b,
                                float* __restrict__ out) {
    __shared__ float sw[4][CAP];
    __shared__ int   ss[4][CAP];
    int wid = (blockIdx.x * blockDim.x + threadIdx.x) >> 6;
    int lane = threadIdx.x & 63;
    int wv = (threadIdx.x >> 6) & 3;
    int slot = lane >> 4, k = lane & 15;
    if (wid >= NODES) return;
    const int beg = rowptr[wid], deg = rowptr[wid + 1] - beg;
    const float adv = ad_[wid];
    float m = NEGF;
    for (int i = lane; i < deg; i += 64) {
        int s = srcs[beg + i];
        float v = as_[s] + adv;
        v = (v >= 0.f) ? v : 0.2f * v;
        if (i < CAP) { sw[wv][i] = v; ss[wv][i] = s; }
        m = fmaxf(m, v);
    }
    #pragma unroll
    for (int off = 32; off; off >>= 1) m = fmaxf(m, __shfl_xor(m, off));
    float den = 0.f;
    for (int i = lane; i < deg; i += 64) {
        float v;
        if (i < CAP) v = sw[wv][i];
        else { int s = srcs[beg + i]; v = as_[s] + adv; v = (v >= 0.f) ? v : 0.2f * v; }
        float w = __expf(v - m);
        if (i < CAP) sw[wv][i] = w;
        den += w;
    }
    #pragma unroll
    for (int off = 32; off; off >>= 1) den += __shfl_xor(den, off);
    const float invd = 1.f / (den + 1e-16f);
    float acc = 0.f;
    const int nl = deg < CAP ? deg : CAP;
    for (int i = slot; i < nl; i += 4) {
        acc += sw[wv][i] * H[(size_t)ss[wv][i] * 16 + k];
    }
    for (int j = CAP + slot; j < deg; j += 4) {   // fallback, ~never taken
        int s = srcs[beg + j];
        float v = as_[s] + adv; v = (v >= 0.f) ? v : 0.2f * v;
        acc += __expf(v - m) * H[(size_t)s * 16 + k];
    }
    acc += __shfl_xor(acc, 16);
    acc += __shfl_xor(acc, 32);
    float v = acc * invd + b[k];
    float mx = v;
    #pragma unroll
    for (int off = 1; off < 16; off <<= 1) mx = fmaxf(mx, __shfl_xor(mx, off));
    float ex = __expf(v - mx), ssum = ex;
    #pragma unroll
    for (int off = 1; off < 16; off <<= 1) ssum += __shfl_xor(ssum, off);
    float r = v - mx - __logf(ssum);
    if (lane < 16) out[(size_t)wid * 16 + k] = r;
}

extern "C" void kernel_launch(void* const* d_in, const int* in_sizes, int n_in,
                              void* d_out, int out_size, void* d_ws, size_t ws_size,
                              hipStream_t stream) {
    const float* x      = (const float*)d_in[0];
    const int*   ei     = (const int*)d_in[1];   // [2, E] int32 on device
    const float* W1     = (const float*)d_in[2];
    const float* a_src1 = (const float*)d_in[3];
    const float* a_dst1 = (const float*)d_in[4];
    const float* b1     = (const float*)d_in[5];
    const float* W2     = (const float*)d_in[6];
    const float* a_src2 = (const float*)d_in[7];
    const float* a_dst2 = (const float*)d_in[8];
    const float* b2     = (const float*)d_in[9];
    float* out = (float*)d_out;

    // ---- workspace layout ----
    float* p = (float*)d_ws;
    ushort_t* h1b = (ushort_t*)p; p += (size_t)NODES * 64;   // 12.8 MB as bf16
    float* agg1   = p; p += (size_t)NODES * 128;             // 25.6 MB
    float* h2     = p; p += (size_t)NODES * 16;              //  3.2 MB
    float* as_    = p; p += NODES;
    float* ad_    = p; p += NODES;
    int* ip = (int*)p;
    int* deg    = ip; ip += NODES;
    int* cursor = ip; ip += NODES;
    int* rowptr = ip; ip += NODES + 1;
    ushort_t* srcs = (ushort_t*)ip; ip += (ETOT + 1) / 2;
    int* bsum   = ip; ip += 256;

    const int EB = (ETOT + 255) / 256;
    const int NB = (NODES + 255) / 256;   // 196 chunks
    const int WAVEGRID = (NODES * 64 + 255) / 256;

    // ---- CSR build prefix (hist + scan) ----
    hipMemsetAsync(deg, 0, NODES * sizeof(int), stream);
    csr_hist<<<EB, 256, 0, stream>>>(ei, deg);
    scan1<<<NB, 256, 0, stream>>>(deg, bsum);
    scan2<<<1, 256, 0, stream>>>(bsum, NB);
    scan3<<<NB, 256, 0, stream>>>(deg, bsum, rowptr, cursor);

    // ---- fused: csr_fill + GEMM1+alpha (independent work, one dispatch) ----
    gemm1_fill<<<FB + GBLK, 256, 0, stream>>>(x, W1, a_src1, a_dst1, h1b, as_, ad_,
                                              ei, cursor, srcs, NODES);

    // ---- layer 1 aggregate ----
    gat_fused128<<<WAVEGRID, 256, 0, stream>>>(rowptr, srcs, as_, ad_, h1b, b1, agg1);

    // ---- layer 2 ----
    gemm_hw2_alpha<<<(NODES * 16 + 255) / 256, 256, 0, stream>>>(agg1, W2, a_src2, a_dst2, h2, as_, ad_, NODES);
    gat_fused16_lsm<<<WAVEGRID, 256, 0, stream>>>(rowptr, srcs, as_, ad_, h2, b2, out);
}

// Round 10
// 209.288 us; speedup vs baseline: 11.5851x; 1.1027x over previous
//
#include <hip/hip_runtime.h>
#include <math.h>

#define NODES 50000
#define NEDGE 800000
#define ETOT  (NEDGE + NODES)
#define NEGF  -1e30f   // finite -inf sentinel
#define CAP   96       // per-wave LDS edge cache (max degree ~45 for this graph)
#define FB    ((ETOT + 255) / 256)    // fill-role blocks (3323)
#define GBLK  ((NODES + 31) / 32)     // gemm-role blocks (1563)

typedef unsigned short ushort_t;
typedef unsigned int uint_t;

__device__ __forceinline__ ushort_t f2bf(float f) {   // fp32 -> bf16 RNE
    uint_t u = __float_as_uint(f);
    return (ushort_t)((u + 0x7fffu + ((u >> 16) & 1u)) >> 16);
}

// ---- fused csr_fill + GEMM1+alpha, INTERLEAVED: even blocks fill, odd gemm ----
// gemm role: 32 rows/block, 256 thr, acc[4][4] over 4 CONTIGUOUS cols (float4 W)
__global__ void gemm1_fill(const float* __restrict__ X, const float* __restrict__ W,
                           const float* __restrict__ a_src, const float* __restrict__ a_dst,
                           ushort_t* __restrict__ Hb, float* __restrict__ as_,
                           float* __restrict__ ad_,
                           const int* __restrict__ ei, int* __restrict__ cursor,
                           ushort_t* __restrict__ srcs, int n) {
    __shared__ float xs[32][132];      // stride 132: 16B-aligned rows for b128 reads
    const uint_t bx = blockIdx.x;
    if ((bx & 1u) == 0u) {
        // ---- csr_fill role (bx even; f = bx/2 in [0,FB)) ----
        int e = (int)(bx >> 1) * 256 + threadIdx.x;
        if (e < ETOT) {
            int s, d;
            if (e < NEDGE) { s = ei[e]; d = ei[NEDGE + e]; }
            else           { s = d = e - NEDGE; }
            int pos = atomicAdd(&cursor[d], 1);
            srcs[pos] = (ushort_t)s;
        }
        return;
    }
    // ---- gemm role (bx odd; g = bx/2, valid if g < GBLK) ----
    const int g = (int)(bx >> 1);
    if (g >= GBLK) return;
    const int t = threadIdx.x;         // 0..255
    const int ct = t & 31;             // cols 4*ct .. 4*ct+3 (contiguous)
    const int rg = t >> 5;             // row group 0..7 -> rows rg*4..rg*4+3
    const int row0 = g * 32;
    #pragma unroll
    for (int i = 0; i < 16; ++i) {
        int idx = i * 256 + t;
        int r = idx >> 7, c = idx & 127;
        int row = row0 + r;
        xs[r][c] = (row < n) ? X[(size_t)row * 128 + c] : 0.f;
    }
    __syncthreads();
    float acc[4][4];
    #pragma unroll
    for (int r = 0; r < 4; ++r)
        #pragma unroll
        for (int c = 0; c < 4; ++c) acc[r][c] = 0.f;

    const float* Wp = W + 4 * ct;
    for (int k4 = 0; k4 < 32; ++k4) {
        float4 w0 = *(const float4*)(Wp + (size_t)(k4 * 4 + 0) * 128);
        float4 w1 = *(const float4*)(Wp + (size_t)(k4 * 4 + 1) * 128);
        float4 w2 = *(const float4*)(Wp + (size_t)(k4 * 4 + 2) * 128);
        float4 w3 = *(const float4*)(Wp + (size_t)(k4 * 4 + 3) * 128);
        float4 xv[4];
        #pragma unroll
        for (int r = 0; r < 4; ++r)
            xv[r] = *(const float4*)(&xs[rg * 4 + r][k4 * 4]);
        #pragma unroll
        for (int r = 0; r < 4; ++r) {
            acc[r][0] += xv[r].x * w0.x + xv[r].y * w1.x + xv[r].z * w2.x + xv[r].w * w3.x;
            acc[r][1] += xv[r].x * w0.y + xv[r].y * w1.y + xv[r].z * w2.y + xv[r].w * w3.y;
            acc[r][2] += xv[r].x * w0.z + xv[r].y * w1.z + xv[r].z * w2.z + xv[r].w * w3.z;
            acc[r][3] += xv[r].x * w0.w + xv[r].y * w1.w + xv[r].z * w2.w + xv[r].w * w3.w;
        }
    }
    const float4 asv = *(const float4*)(a_src + 4 * ct);
    const float4 adv = *(const float4*)(a_dst + 4 * ct);
    #pragma unroll
    for (int r = 0; r < 4; ++r) {
        int row = row0 + rg * 4 + r;
        bool ok = row < n;
        if (ok) {
            uint_t lo = (uint_t)f2bf(acc[r][0]) | ((uint_t)f2bf(acc[r][1]) << 16);
            uint_t hi = (uint_t)f2bf(acc[r][2]) | ((uint_t)f2bf(acc[r][3]) << 16);
            uint2 pk; pk.x = lo; pk.y = hi;
            *(uint2*)(Hb + (size_t)row * 128 + 4 * ct) = pk;
        }
        float s = acc[r][0] * asv.x + acc[r][1] * asv.y + acc[r][2] * asv.z + acc[r][3] * asv.w;
        float d = acc[r][0] * adv.x + acc[r][1] * adv.y + acc[r][2] * adv.z + acc[r][3] * adv.w;
        #pragma unroll
        for (int off = 16; off; off >>= 1) {            // reduce across the 32-lane col group
            s += __shfl_down(s, off, 32);
            d += __shfl_down(d, off, 32);
        }
        if (ct == 0 && ok) { as_[row] = s; ad_[row] = d; }
    }
}

// ---- GEMM2 + fused alpha: H2[n,16] = Hin @ W2 (W2 staged in LDS) ----
__global__ void gemm_hw2_alpha(const float* __restrict__ Hin, const float* __restrict__ W,
                               const float* __restrict__ a_src, const float* __restrict__ a_dst,
                               float* __restrict__ Hout, float* __restrict__ as_,
                               float* __restrict__ ad_, int n) {
    __shared__ float wl[128 * 16];
    for (int i = threadIdx.x; i < 128 * 16; i += 256) wl[i] = W[i];
    __syncthreads();
    int tid = blockIdx.x * blockDim.x + threadIdx.x;
    int node = tid >> 4, col = tid & 15;
    if (node >= n) return;
    const float* hr = Hin + (size_t)node * 128;
    float acc = 0.f;
    #pragma unroll
    for (int k = 0; k < 128; ++k) acc += hr[k] * wl[k * 16 + col];
    Hout[(size_t)node * 16 + col] = acc;
    float ps = acc * a_src[col], pd = acc * a_dst[col];
    #pragma unroll
    for (int off = 1; off < 16; off <<= 1) {
        ps += __shfl_xor(ps, off);
        pd += __shfl_xor(pd, off);
    }
    if (col == 0) { as_[node] = ps; ad_[node] = pd; }
}

// =================== CSR build ====================
__global__ void csr_hist(const int* __restrict__ ei, int* __restrict__ deg) {
    int e = blockIdx.x * blockDim.x + threadIdx.x;
    if (e >= ETOT) return;
    int d = (e < NEDGE) ? ei[NEDGE + e] : e - NEDGE;
    atomicAdd(&deg[d], 1);
}

__global__ void scan1(const int* __restrict__ deg, int* __restrict__ bsum) {
    int i = blockIdx.x * 256 + threadIdx.x;
    int v = (i < NODES) ? deg[i] : 0;
    #pragma unroll
    for (int off = 32; off; off >>= 1) v += __shfl_down(v, off);
    __shared__ int ws[4];
    if ((threadIdx.x & 63) == 0) ws[threadIdx.x >> 6] = v;
    __syncthreads();
    if (threadIdx.x == 0) bsum[blockIdx.x] = ws[0] + ws[1] + ws[2] + ws[3];
}

__global__ void scan2(int* __restrict__ bsum, int nb) {
    int t = threadIdx.x;
    int lane = t & 63, w = t >> 6;
    int v = (t < nb) ? bsum[t] : 0;
    int sv = v;
    #pragma unroll
    for (int off = 1; off < 64; off <<= 1) {
        int o = __shfl_up(sv, off);
        if (lane >= off) sv += o;
    }
    __shared__ int wsum[4];
    if (lane == 63) wsum[w] = sv;
    __syncthreads();
    int add = 0;
    for (int j = 0; j < w; ++j) add += wsum[j];
    sv += add;
    if (t < nb) bsum[t] = sv - v;   // exclusive
}

__global__ void scan3(const int* __restrict__ deg, const int* __restrict__ bsum,
                      int* __restrict__ rowptr, int* __restrict__ cursor) {
    int i = blockIdx.x * 256 + threadIdx.x;
    int v = (i < NODES) ? deg[i] : 0;
    int lane = threadIdx.x & 63, w = threadIdx.x >> 6;
    int sv = v;
    #pragma unroll
    for (int off = 1; off < 64; off <<= 1) {
        int o = __shfl_up(sv, off);
        if (lane >= off) sv += o;
    }
    __shared__ int wsum[4];
    if (lane == 63) wsum[w] = sv;
    __syncthreads();
    int add = bsum[blockIdx.x];
    for (int j = 0; j < w; ++j) add += wsum[j];
    int excl = add + sv - v;
    if (i < NODES) { rowptr[i] = excl; cursor[i] = excl; }
    if (i == NODES - 1) rowptr[NODES] = excl + v;
}

// ---- layer 1: fused softmax + weighted bf16 gather + bias + ReLU (F=128) ----
__global__ void gat_fused128(const int* __restrict__ rowptr, const ushort_t* __restrict__ srcs,
                             const float* __restrict__ as_, const float* __restrict__ ad_,
                             const ushort_t* __restrict__ Hb, const float* __restrict__ b,
                             float* __restrict__ out) {
    __shared__ float sw[4][CAP];
    __shared__ int   ss[4][CAP];
    int wid = (blockIdx.x * blockDim.x + threadIdx.x) >> 6;
    int lane = threadIdx.x & 63;
    int wv = (threadIdx.x >> 6) & 3;
    if (wid >= NODES) return;
    const int beg = rowptr[wid], deg = rowptr[wid + 1] - beg;
    const float adv = ad_[wid];
    float m = NEGF;
    for (int i = lane; i < deg; i += 64) {
        int s = srcs[beg + i];
        float v = as_[s] + adv;
        v = (v >= 0.f) ? v : 0.2f * v;
        if (i < CAP) { sw[wv][i] = v; ss[wv][i] = s; }
        m = fmaxf(m, v);
    }
    #pragma unroll
    for (int off = 32; off; off >>= 1) m = fmaxf(m, __shfl_xor(m, off));
    float den = 0.f;
    for (int i = lane; i < deg; i += 64) {
        float v;
        if (i < CAP) v = sw[wv][i];
        else { int s = srcs[beg + i]; v = as_[s] + adv; v = (v >= 0.f) ? v : 0.2f * v; }
        float w = __expf(v - m);
        if (i < CAP) sw[wv][i] = w;
        den += w;
    }
    #pragma unroll
    for (int off = 32; off; off >>= 1) den += __shfl_xor(den, off);
    const float invd = 1.f / (den + 1e-16f);
    // phase 2: weighted gather of bf16 rows; lane covers features {2l, 2l+1}
    float ax = 0.f, ay = 0.f;
    const int nl = deg < CAP ? deg : CAP;
    int i = 0;
    for (; i + 4 <= nl; i += 4) {
        float w0 = sw[wv][i], w1 = sw[wv][i + 1], w2 = sw[wv][i + 2], w3 = sw[wv][i + 3];
        int s0 = ss[wv][i], s1 = ss[wv][i + 1], s2 = ss[wv][i + 2], s3 = ss[wv][i + 3];
        uint_t u0 = *(const uint_t*)(Hb + (size_t)s0 * 128 + lane * 2);
        uint_t u1 = *(const uint_t*)(Hb + (size_t)s1 * 128 + lane * 2);
        uint_t u2 = *(const uint_t*)(Hb + (size_t)s2 * 128 + lane * 2);
        uint_t u3 = *(const uint_t*)(Hb + (size_t)s3 * 128 + lane * 2);
        ax += w0 * __uint_as_float(u0 << 16) + w1 * __uint_as_float(u1 << 16)
            + w2 * __uint_as_float(u2 << 16) + w3 * __uint_as_float(u3 << 16);
        ay += w0 * __uint_as_float(u0 & 0xffff0000u) + w1 * __uint_as_float(u1 & 0xffff0000u)
            + w2 * __uint_as_float(u2 & 0xffff0000u) + w3 * __uint_as_float(u3 & 0xffff0000u);
    }
    for (; i < nl; ++i) {
        float w0 = sw[wv][i];
        int s0 = ss[wv][i];
        uint_t u0 = *(const uint_t*)(Hb + (size_t)s0 * 128 + lane * 2);
        ax += w0 * __uint_as_float(u0 << 16);
        ay += w0 * __uint_as_float(u0 & 0xffff0000u);
    }
    for (int j = CAP; j < deg; ++j) {   // correctness fallback, ~never taken
        int s0 = srcs[beg + j];
        float v = as_[s0] + adv; v = (v >= 0.f) ? v : 0.2f * v;
        float w0 = __expf(v - m);
        uint_t u0 = *(const uint_t*)(Hb + (size_t)s0 * 128 + lane * 2);
        ax += w0 * __uint_as_float(u0 << 16);
        ay += w0 * __uint_as_float(u0 & 0xffff0000u);
    }
    float2 o;
    o.x = fmaxf(ax * invd + b[lane * 2], 0.f);
    o.y = fmaxf(ay * invd + b[lane * 2 + 1], 0.f);
    *(float2*)(out + (size_t)wid * 128 + lane * 2) = o;
}

// ---- layer 2: fused softmax + aggregate (F=16, 4 slots/wave) + bias + lsm ----
__global__ void gat_fused16_lsm(const int* __restrict__ rowptr, const ushort_t* __restrict__ srcs,
                                const float* __restrict__ as_, const float* __restrict__ ad_,
                                const float* __restrict__ H, const float* __restrict__ b,
                                float* __restrict__ out) {
    __shared__ float sw[4][CAP];
    __shared__ int   ss[4][CAP];
    int wid = (blockIdx.x * blockDim.x + threadIdx.x) >> 6;
    int lane = threadIdx.x & 63;
    int wv = (threadIdx.x >> 6) & 3;
    int slot = lane >> 4, k = lane & 15;
    if (wid >= NODES) return;
    const int beg = rowptr[wid], deg = rowptr[wid + 1] - beg;
    const float adv = ad_[wid];
    float m = NEGF;
    for (int i = lane; i < deg; i += 64) {
        int s = srcs[beg + i];
        float v = as_[s] + adv;
        v = (v >= 0.f) ? v : 0.2f * v;
        if (i < CAP) { sw[wv][i] = v; ss[wv][i] = s; }
        m = fmaxf(m, v);
    }
    #pragma unroll
    for (int off = 32; off; off >>= 1) m = fmaxf(m, __shfl_xor(m, off));
    float den = 0.f;
    for (int i = lane; i < deg; i += 64) {
        float v;
        if (i < CAP) v = sw[wv][i];
        else { int s = srcs[beg + i]; v = as_[s] + adv; v = (v >= 0.f) ? v : 0.2f * v; }
        float w = __expf(v - m);
        if (i < CAP) sw[wv][i] = w;
        den += w;
    }
    #pragma unroll
    for (int off = 32; off; off >>= 1) den += __shfl_xor(den, off);
    const float invd = 1.f / (den + 1e-16f);
    float acc = 0.f;
    const int nl = deg < CAP ? deg : CAP;
    for (int i = slot; i < nl; i += 4) {
        acc += sw[wv][i] * H[(size_t)ss[wv][i] * 16 + k];
    }
    for (int j = CAP + slot; j < deg; j += 4) {   // fallback, ~never taken
        int s = srcs[beg + j];
        float v = as_[s] + adv; v = (v >= 0.f) ? v : 0.2f * v;
        acc += __expf(v - m) * H[(size_t)s * 16 + k];
    }
    acc += __shfl_xor(acc, 16);
    acc += __shfl_xor(acc, 32);
    float v = acc * invd + b[k];
    float mx = v;
    #pragma unroll
    for (int off = 1; off < 16; off <<= 1) mx = fmaxf(mx, __shfl_xor(mx, off));
    float ex = __expf(v - mx), ssum = ex;
    #pragma unroll
    for (int off = 1; off < 16; off <<= 1) ssum += __shfl_xor(ssum, off);
    float r = v - mx - __logf(ssum);
    if (lane < 16) out[(size_t)wid * 16 + k] = r;
}

extern "C" void kernel_launch(void* const* d_in, const int* in_sizes, int n_in,
                              void* d_out, int out_size, void* d_ws, size_t ws_size,
                              hipStream_t stream) {
    const float* x      = (const float*)d_in[0];
    const int*   ei     = (const int*)d_in[1];   // [2, E] int32 on device
    const float* W1     = (const float*)d_in[2];
    const float* a_src1 = (const float*)d_in[3];
    const float* a_dst1 = (const float*)d_in[4];
    const float* b1     = (const float*)d_in[5];
    const float* W2     = (const float*)d_in[6];
    const float* a_src2 = (const float*)d_in[7];
    const float* a_dst2 = (const float*)d_in[8];
    const float* b2     = (const float*)d_in[9];
    float* out = (float*)d_out;

    // ---- workspace layout ----
    float* p = (float*)d_ws;
    ushort_t* h1b = (ushort_t*)p; p += (size_t)NODES * 64;   // 12.8 MB as bf16
    float* agg1   = p; p += (size_t)NODES * 128;             // 25.6 MB
    float* h2     = p; p += (size_t)NODES * 16;              //  3.2 MB
    float* as_    = p; p += NODES;
    float* ad_    = p; p += NODES;
    int* ip = (int*)p;
    int* deg    = ip; ip += NODES;
    int* cursor = ip; ip += NODES;
    int* rowptr = ip; ip += NODES + 1;
    ushort_t* srcs = (ushort_t*)ip; ip += (ETOT + 1) / 2;
    int* bsum   = ip; ip += 256;

    const int EB = (ETOT + 255) / 256;
    const int NB = (NODES + 255) / 256;   // 196 chunks
    const int WAVEGRID = (NODES * 64 + 255) / 256;

    // ---- CSR build prefix (hist + scan) ----
    hipMemsetAsync(deg, 0, NODES * sizeof(int), stream);
    csr_hist<<<EB, 256, 0, stream>>>(ei, deg);
    scan1<<<NB, 256, 0, stream>>>(deg, bsum);
    scan2<<<1, 256, 0, stream>>>(bsum, NB);
    scan3<<<NB, 256, 0, stream>>>(deg, bsum, rowptr, cursor);

    // ---- fused fill+gemm, interleaved even/odd blocks for true co-residency ----
    gemm1_fill<<<2 * FB, 256, 0, stream>>>(x, W1, a_src1, a_dst1, h1b, as_, ad_,
                                           ei, cursor, srcs, NODES);

    // ---- layer 1 aggregate ----
    gat_fused128<<<WAVEGRID, 256, 0, stream>>>(rowptr, srcs, as_, ad_, h1b, b1, agg1);

    // ---- layer 2 ----
    gemm_hw2_alpha<<<(NODES * 16 + 255) / 256, 256, 0, stream>>>(agg1, W2, a_src2, a_dst2, h2, as_, ad_, NODES);
    gat_fused16_lsm<<<WAVEGRID, 256, 0, stream>>>(rowptr, srcs, as_, ad_, h2, b2, out);
}